// Round 1
// baseline (313.328 us; speedup 1.0000x reference)
//
#include <hip/hip_runtime.h>
#include <math.h>

#define N 1024
#define BATCH 8
#define THREADS 256

// ws layout (float index):
//  [0,1024)        colsumM
//  [1024,2048)     sf_re
//  [2048,3072)     sf_im
//  [3072]          sumM2
//  [3073]          maxM (float bits, atomicMax as uint)
//  [3584,11776)    rowsum[b][m]   (8*1024)
//  [11776,19968)   colsumT[b][k]  (8*1024)
//  [19968,19976)   sumMT[b]
//  [19976,19984)   sumTT[b]
#define OFF_COLSUMM 0
#define OFF_SFRE    1024
#define OFF_SFIM    2048
#define OFF_SUMM2   3072
#define OFF_MAXM    3073
#define OFF_ROWSUM  3584
#define OFF_COLSUMT 11776
#define OFF_SUMMT   19968
#define OFF_SUMTT   19976
#define WS_FLOATS   19984

__device__ __forceinline__ float wave_sum(float v) {
    #pragma unroll
    for (int o = 32; o > 0; o >>= 1) v += __shfl_down(v, o, 64);
    return v;
}
__device__ __forceinline__ float wave_max(float v) {
    #pragma unroll
    for (int o = 32; o > 0; o >>= 1) v = fmaxf(v, __shfl_down(v, o, 64));
    return v;
}

// Precompute sf[j] = exp(-i * 2*W_CENTER*TS * (j-512)) in double precision.
// (The constant-phase part is irrelevant under abs(), but cost is zero.)
__global__ void k_sf(float* ws) {
    int j = blockIdx.x * THREADS + threadIdx.x;
    if (j >= N) return;
    double ang = -2.0 * 337.927 * 1.5 * (double)(j - 512);
    double s, c;
    sincos(ang, &s, &c);
    ws[OFF_SFRE + j] = (float)c;
    ws[OFF_SFIM + j] = (float)s;
}

// Spectrogram stats: colsumM[j], sum(M^2), max(M). 256 blocks x 4 rows each.
__global__ __launch_bounds__(THREADS) void k_mstats(const float* __restrict__ M, float* ws) {
    int t = threadIdx.x;
    int r0 = blockIdx.x * 4;
    float cs[4] = {0.f, 0.f, 0.f, 0.f};
    float sq = 0.f, mx = 0.f;
    for (int r = 0; r < 4; ++r) {
        const float* row = M + (size_t)(r0 + r) * N;
        #pragma unroll
        for (int q = 0; q < 4; ++q) {
            float v = row[t + THREADS * q];
            cs[q] += v;
            sq += v * v;
            mx = fmaxf(mx, v);
        }
    }
    #pragma unroll
    for (int q = 0; q < 4; ++q) atomicAdd(&ws[OFF_COLSUMM + t + THREADS * q], cs[q]);

    sq = wave_sum(sq);
    mx = wave_max(mx);
    __shared__ float rs_[4], rm_[4];
    int wid = t >> 6, lane = t & 63;
    if (lane == 0) { rs_[wid] = sq; rm_[wid] = mx; }
    __syncthreads();
    if (t == 0) {
        float S = rs_[0] + rs_[1] + rs_[2] + rs_[3];
        float X = fmaxf(fmaxf(rm_[0], rm_[1]), fmaxf(rm_[2], rm_[3]));
        atomicAdd(&ws[OFF_SUMM2], S);
        atomicMax((unsigned int*)ws + OFF_MAXM, __float_as_uint(X));
    }
}

// One block per (delay row m, batch b): build product, 1024-pt FFT in LDS,
// magnitudes, fused reductions.
__global__ __launch_bounds__(THREADS) void k_row(const float* __restrict__ pred,
                                                 const float* __restrict__ M,
                                                 float* ws) {
    __shared__ float yre[N], yim[N], wre[N], wim[N];
    __shared__ float red[3][4];
    const int t = threadIdx.x;
    const int m = blockIdx.x;
    const int b = blockIdx.y;

    const float* pr = pred + (size_t)b * 2 * N;
    #pragma unroll
    for (int q = 0; q < 4; ++q) {
        int j = t + THREADS * q;
        yre[j] = pr[j];
        yim[j] = pr[N + j];
    }
    __syncthreads();

    // product: p[j] = y[j] * y[(j - (m-512)) % N] * sf[j]
    const float* sfr = ws + OFF_SFRE;
    const float* sfi = ws + OFF_SFIM;
    #pragma unroll
    for (int q = 0; q < 4; ++q) {
        int j = t + THREADS * q;
        int s = (j - m + 512) & (N - 1);
        float ar = yre[j], ai = yim[j];
        float br = yre[s], bi = yim[s];
        float p_r = ar * br - ai * bi;
        float p_i = ar * bi + ai * br;
        float cr = sfr[j], ci = sfi[j];
        wre[j] = p_r * cr - p_i * ci;
        wim[j] = p_r * ci + p_i * cr;
    }

    // radix-2 DIF FFT, 10 stages, output in bit-reversed order
    const float PI_F = 3.14159265358979323846f;
    for (int h = 512; h >= 1; h >>= 1) {
        __syncthreads();
        #pragma unroll 2
        for (int rr = 0; rr < 2; ++rr) {
            int tt = t + rr * THREADS;        // 0..511 butterfly id
            int pos = tt & (h - 1);
            int i0 = 2 * tt - pos;            // grp*2h + pos
            int i1 = i0 + h;
            float are = wre[i0], aim = wim[i0];
            float bre = wre[i1], bim = wim[i1];
            float dre = are - bre, dim_ = aim - bim;
            wre[i0] = are + bre;
            wim[i0] = aim + bim;
            float ang = -PI_F * (float)pos / (float)h;
            float sn, cn;
            __sincosf(ang, &sn, &cn);
            wre[i1] = dre * cn - dim_ * sn;
            wim[i1] = dre * sn + dim_ * cn;
        }
    }
    __syncthreads();

    // magnitudes into yre (y no longer needed): Tref[m, c] with c = bitrev(p)^512
    #pragma unroll
    for (int q = 0; q < 4; ++q) {
        int p = t + THREADS * q;
        int k = __brev((unsigned)p) >> 22;
        int c = k ^ 512;
        float xr = wre[p], xi = wim[p];
        yre[c] = 1.5f * sqrtf(xr * xr + xi * xi);
    }
    __syncthreads();

    // fused reductions over this row
    const float* Mrow = M + (size_t)m * N;
    float* colT = ws + OFF_COLSUMT + b * N;
    float rs = 0.f, mt = 0.f, tt2 = 0.f;
    #pragma unroll
    for (int q = 0; q < 4; ++q) {
        int c = t + THREADS * q;
        float v = yre[c];
        rs += v;
        tt2 += v * v;
        mt += Mrow[c] * v;
        atomicAdd(&colT[c], v);
    }
    rs = wave_sum(rs);
    mt = wave_sum(mt);
    tt2 = wave_sum(tt2);
    int wid = t >> 6, lane = t & 63;
    if (lane == 0) { red[0][wid] = rs; red[1][wid] = mt; red[2][wid] = tt2; }
    __syncthreads();
    if (t == 0) {
        float R  = red[0][0] + red[0][1] + red[0][2] + red[0][3];
        float MT = red[1][0] + red[1][1] + red[1][2] + red[1][3];
        float TT = red[2][0] + red[2][1] + red[2][2] + red[2][3];
        ws[OFF_ROWSUM + b * N + m] = R;
        atomicAdd(&ws[OFF_SUMMT + b], MT);
        atomicAdd(&ws[OFF_SUMTT + b], TT);
    }
}

// Finalize: mu, r, err per batch; mean over batch.
__global__ __launch_bounds__(THREADS) void k_final(float* ws, float* out) {
    __shared__ double redn[4], redd[4];
    const int t = threadIdx.x;
    const int wid = t >> 6, lane = t & 63;
    double emean = 0.0;
    const float sumM2 = ws[OFF_SUMM2];
    const float mx = ws[OFF_MAXM];  // float bits written via uint atomicMax
    const double norm = (double)N * (double)N * (double)mx * (double)mx;
    for (int b = 0; b < BATCH; ++b) {
        const float* rowsum = ws + OFF_ROWSUM + b * N;
        const float* colT = ws + OFF_COLSUMT + b * N;
        double num = 0.0, den = 0.0;
        for (int j = t; j < N; j += THREADS) {
            double r = (double)rowsum[j];
            num += (double)ws[OFF_COLSUMM + j] * r;
            den += (double)colT[j] * r;
        }
        #pragma unroll
        for (int o = 32; o > 0; o >>= 1) {
            num += __shfl_down(num, o, 64);
            den += __shfl_down(den, o, 64);
        }
        if (lane == 0) { redn[wid] = num; redd[wid] = den; }
        __syncthreads();
        if (t == 0) {
            double NUM = redn[0] + redn[1] + redn[2] + redn[3];
            double DEN = redd[0] + redd[1] + redd[2] + redd[3];
            double mu = NUM / DEN;
            double r = (double)sumM2 - 2.0 * mu * (double)ws[OFF_SUMMT + b]
                     + mu * mu * (double)ws[OFF_SUMTT + b];
            emean += sqrt(r / norm);
        }
        __syncthreads();
    }
    if (t == 0) out[0] = (float)(emean / (double)BATCH);
}

extern "C" void kernel_launch(void* const* d_in, const int* in_sizes, int n_in,
                              void* d_out, int out_size, void* d_ws, size_t ws_size,
                              hipStream_t stream) {
    const float* pred = (const float*)d_in[0];   // [8, 2048]
    // d_in[1] = label, unused by the returned loss
    const float* M = (const float*)d_in[2];      // [1024, 1024]
    float* ws = (float*)d_ws;
    float* out = (float*)d_out;

    hipMemsetAsync(d_ws, 0, WS_FLOATS * sizeof(float), stream);
    k_sf<<<(N + THREADS - 1) / THREADS, THREADS, 0, stream>>>(ws);
    k_mstats<<<N / 4, THREADS, 0, stream>>>(M, ws);
    dim3 grid(N, BATCH);
    k_row<<<grid, THREADS, 0, stream>>>(pred, M, ws);
    k_final<<<1, THREADS, 0, stream>>>(ws, out);
}

// Round 2
// 237.571 us; speedup vs baseline: 1.3189x; 1.3189x over previous
//
#include <hip/hip_runtime.h>
#include <math.h>

#define N 1024
#define B_ 8
#define T_ 256
#define NREP 4

// ws layout (float index)
#define OFF_SF      0        // 1024 x float2 (interleaved)          [0, 2048)
#define OFF_TW      2048     // 4 stages x 256 x 8 floats            [2048, 10240)
#define OFF_ROWSUM  10240    // 8 x 1024                             [10240, 18432)
#define ZERO_START  18432
#define OFF_COLSUMM 18432    // 1024
#define OFF_SUMM2   19456
#define OFF_MAXM    19457
#define OFF_SUMMT   19464    // 8
#define OFF_SUMTT   19472    // 8
#define OFF_COLT    20480    // 8 batches x NREP x 1024              [20480, 53248)
#define WS_END      (OFF_COLT + B_ * NREP * N)

// per-transition LDS swizzles (bijective XOR of high addr bits into bank bits)
#define S1(a) ((a) ^ (((a) >> 2) & 0x10))
#define S2(a) ((a) ^ (((a) >> 3) & 0x0C))
#define S3(a) ((a) ^ (((a) >> 5) & 0x07))
#define S4(a) ((a) ^ (((a) >> 5) & 0x07))

__device__ __forceinline__ float wave_sum(float v) {
    #pragma unroll
    for (int o = 32; o > 0; o >>= 1) v += __shfl_down(v, o, 64);
    return v;
}
__device__ __forceinline__ float wave_max(float v) {
    #pragma unroll
    for (int o = 32; o > 0; o >>= 1) v = fmaxf(v, __shfl_down(v, o, 64));
    return v;
}

__device__ __forceinline__ void load_tw(float tw[6], const float* __restrict__ p) {
    float4 v = *(const float4*)p;
    float2 w = *(const float2*)(p + 4);
    tw[0] = v.x; tw[1] = v.y; tw[2] = v.z; tw[3] = v.w; tw[4] = w.x; tw[5] = w.y;
}

// forward radix-4 DIF butterfly + twiddles (W^pos, W^2pos, W^3pos), in place
__device__ __forceinline__ void bfly4(float xr[4], float xi[4], const float tw[6]) {
    float t0r = xr[0] + xr[2], t0i = xi[0] + xi[2];
    float t1r = xr[0] - xr[2], t1i = xi[0] - xi[2];
    float t2r = xr[1] + xr[3], t2i = xi[1] + xi[3];
    float t3r = xr[1] - xr[3], t3i = xi[1] - xi[3];
    float y1r = t1r + t3i, y1i = t1i - t3r;
    float y2r = t0r - t2r, y2i = t0i - t2i;
    float y3r = t1r - t3i, y3i = t1i + t3r;
    xr[0] = t0r + t2r;            xi[0] = t0i + t2i;
    xr[1] = y1r * tw[0] - y1i * tw[1]; xi[1] = y1r * tw[1] + y1i * tw[0];
    xr[2] = y2r * tw[2] - y2i * tw[3]; xi[2] = y2r * tw[3] + y2i * tw[2];
    xr[3] = y3r * tw[4] - y3i * tw[5]; xi[3] = y3r * tw[5] + y3i * tw[4];
}

// init: blocks 0..1023 -> M row stats; block 1024 -> sf + twiddle packs
__global__ __launch_bounds__(T_) void k_init(const float* __restrict__ M, float* ws) {
    const int t = threadIdx.x;
    const int blk = blockIdx.x;
    if (blk < N) {
        const float* row = M + (size_t)blk * N;
        float sq = 0.f, mx = 0.f;
        #pragma unroll
        for (int q = 0; q < 4; ++q) {
            float v = row[t + T_ * q];
            atomicAdd(&ws[OFF_COLSUMM + t + T_ * q], v);
            sq += v * v;
            mx = fmaxf(mx, v);
        }
        sq = wave_sum(sq);
        mx = wave_max(mx);
        __shared__ float rs_[4], rm_[4];
        int wid = t >> 6, lane = t & 63;
        if (lane == 0) { rs_[wid] = sq; rm_[wid] = mx; }
        __syncthreads();
        if (t == 0) {
            atomicAdd(&ws[OFF_SUMM2], rs_[0] + rs_[1] + rs_[2] + rs_[3]);
            float X = fmaxf(fmaxf(rm_[0], rm_[1]), fmaxf(rm_[2], rm_[3]));
            atomicMax((unsigned int*)ws + OFF_MAXM, __float_as_uint(X));
        }
    } else {
        for (int e = t; e < N; e += T_) {
            double ang = -2.0 * 337.927 * 1.5 * (double)(e - 512);
            double s, c;
            sincos(ang, &s, &c);
            ws[OFF_SF + 2 * e] = (float)c;
            ws[OFF_SF + 2 * e + 1] = (float)s;
        }
        for (int e = t; e < 1024; e += T_) {
            int s = e >> 8, tt = e & 255;
            int h = 256 >> (2 * s);
            int pos = tt & (h - 1);
            int step = 1 << (2 * s);
            double a1 = -2.0 * M_PI * (double)(pos * step) / 1024.0;
            double s1, c1, s2, c2, s3, c3;
            sincos(a1, &s1, &c1);
            sincos(2.0 * a1, &s2, &c2);
            sincos(3.0 * a1, &s3, &c3);
            float* p = ws + OFF_TW + e * 8;
            p[0] = (float)c1; p[1] = (float)s1;
            p[2] = (float)c2; p[3] = (float)s2;
            p[4] = (float)c3; p[5] = (float)s3;
            p[6] = 0.f; p[7] = 0.f;
        }
    }
}

__global__ __launch_bounds__(T_, 6) void k_row(const float* __restrict__ pred,
                                               const float* __restrict__ M,
                                               float* __restrict__ ws) {
    __shared__ float Ar[N], Ai[N], Br[N], Bi[N];
    __shared__ float red[3][4];
    const int t = threadIdx.x;
    const int m = blockIdx.x;
    const int b = blockIdx.y;

    float xr[4], xi[4], tw[6];

    // product + stage 0 (h=256), all in registers
    {
        const float* pr = pred + (size_t)b * 2 * N;
        const float2* sf2 = (const float2*)(ws + OFF_SF);
        #pragma unroll
        for (int q = 0; q < 4; ++q) {
            int j = t + T_ * q;
            int s = (j - m + 512) & (N - 1);
            float ar = pr[j], ai = pr[N + j];
            float br = pr[s], bi = pr[N + s];
            float2 sv = sf2[j];
            float p_r = ar * br - ai * bi;
            float p_i = ar * bi + ai * br;
            xr[q] = p_r * sv.x - p_i * sv.y;
            xi[q] = p_r * sv.y + p_i * sv.x;
        }
        load_tw(tw, ws + OFF_TW + (size_t)t * 8);
        bfly4(xr, xi, tw);
        #pragma unroll
        for (int q = 0; q < 4; ++q) { int a = t + 256 * q; Ar[a] = xr[q]; Ai[a] = xi[q]; }
    }
    __syncthreads();

    // stage 1 (h=64): read A, write B (swizzle S1)
    {
        int base = ((t >> 6) << 8) | (t & 63);
        #pragma unroll
        for (int q = 0; q < 4; ++q) { int a = base + (q << 6); xr[q] = Ar[a]; xi[q] = Ai[a]; }
        load_tw(tw, ws + OFF_TW + (size_t)(256 + t) * 8);
        bfly4(xr, xi, tw);
        #pragma unroll
        for (int q = 0; q < 4; ++q) { int a = S1(base + (q << 6)); Br[a] = xr[q]; Bi[a] = xi[q]; }
    }
    __syncthreads();

    // stage 2 (h=16): read B (S1), write A (S2)
    {
        int base = ((t >> 4) << 6) | (t & 15);
        #pragma unroll
        for (int q = 0; q < 4; ++q) { int a = S1(base + (q << 4)); xr[q] = Br[a]; xi[q] = Bi[a]; }
        load_tw(tw, ws + OFF_TW + (size_t)(512 + t) * 8);
        bfly4(xr, xi, tw);
        #pragma unroll
        for (int q = 0; q < 4; ++q) { int a = S2(base + (q << 4)); Ar[a] = xr[q]; Ai[a] = xi[q]; }
    }
    __syncthreads();

    // stage 3 (h=4): read A (S2), write B (S3)
    {
        int base = ((t >> 2) << 4) | (t & 3);
        #pragma unroll
        for (int q = 0; q < 4; ++q) { int a = S2(base + (q << 2)); xr[q] = Ar[a]; xi[q] = Ai[a]; }
        load_tw(tw, ws + OFF_TW + (size_t)(768 + t) * 8);
        bfly4(xr, xi, tw);
        #pragma unroll
        for (int q = 0; q < 4; ++q) { int a = S3(base + (q << 2)); Br[a] = xr[q]; Bi[a] = xi[q]; }
    }
    __syncthreads();

    // stage 4 (h=1, W=1): read B (S3), magnitudes -> scatter to A (S4)
    {
        int base = t << 2;
        #pragma unroll
        for (int q = 0; q < 4; ++q) { int a = S3(base + q); xr[q] = Br[a]; xi[q] = Bi[a]; }
        float t0r = xr[0] + xr[2], t0i = xi[0] + xi[2];
        float t1r = xr[0] - xr[2], t1i = xi[0] - xi[2];
        float t2r = xr[1] + xr[3], t2i = xi[1] + xi[3];
        float t3r = xr[1] - xr[3], t3i = xi[1] - xi[3];
        float yr[4], yi[4];
        yr[0] = t0r + t2r; yi[0] = t0i + t2i;
        yr[1] = t1r + t3i; yi[1] = t1i - t3r;
        yr[2] = t0r - t2r; yi[2] = t0i - t2i;
        yr[3] = t1r - t3i; yi[3] = t1i + t3r;
        // output position p = 4t+q holds X[k], k = base-4 digit reverse of p
        int r4t = ((t & 3) << 6) | (((t >> 2) & 3) << 4) | (((t >> 4) & 3) << 2) | ((t >> 6) & 3);
        #pragma unroll
        for (int q = 0; q < 4; ++q) {
            int c = ((q << 8) | r4t) ^ 512;
            Ar[S4(c)] = 1.5f * sqrtf(yr[q] * yr[q] + yi[q] * yi[q]);
        }
    }
    __syncthreads();

    // fused reductions: rowsum, sum(M*T), sum(T*T), colT (coalesced)
    {
        const float* Mrow = M + (size_t)m * N;
        float* colT = ws + OFF_COLT + (size_t)(b * NREP + (m & (NREP - 1))) * N;
        float rs = 0.f, mt = 0.f, tt2 = 0.f;
        #pragma unroll
        for (int q = 0; q < 4; ++q) {
            int cc = t + 256 * q;
            float v = Ar[S4(cc)];
            rs += v;
            tt2 += v * v;
            mt += Mrow[cc] * v;
            atomicAdd(&colT[cc], v);
        }
        rs = wave_sum(rs); mt = wave_sum(mt); tt2 = wave_sum(tt2);
        int wid = t >> 6, lane = t & 63;
        if (lane == 0) { red[0][wid] = rs; red[1][wid] = mt; red[2][wid] = tt2; }
        __syncthreads();
        if (t == 0) {
            float R  = red[0][0] + red[0][1] + red[0][2] + red[0][3];
            float MT = red[1][0] + red[1][1] + red[1][2] + red[1][3];
            float TT = red[2][0] + red[2][1] + red[2][2] + red[2][3];
            ws[OFF_ROWSUM + b * N + m] = R;
            atomicAdd(&ws[OFF_SUMMT + b], MT);
            atomicAdd(&ws[OFF_SUMTT + b], TT);
        }
    }
}

__global__ __launch_bounds__(T_) void k_final(float* ws, float* out) {
    __shared__ double redn[4], redd[4];
    const int b = blockIdx.x;
    const int t = threadIdx.x;
    const int wid = t >> 6, lane = t & 63;
    const float* rowsum = ws + OFF_ROWSUM + (size_t)b * N;
    double num = 0.0, den = 0.0;
    #pragma unroll
    for (int q = 0; q < 4; ++q) {
        int j = t + 256 * q;
        double r = (double)rowsum[j];
        float ct = 0.f;
        #pragma unroll
        for (int rep = 0; rep < NREP; ++rep)
            ct += ws[OFF_COLT + (size_t)(b * NREP + rep) * N + j];
        num += (double)ws[OFF_COLSUMM + j] * r;
        den += (double)ct * r;
    }
    #pragma unroll
    for (int o = 32; o > 0; o >>= 1) {
        num += __shfl_down(num, o, 64);
        den += __shfl_down(den, o, 64);
    }
    if (lane == 0) { redn[wid] = num; redd[wid] = den; }
    __syncthreads();
    if (t == 0) {
        double NUM = redn[0] + redn[1] + redn[2] + redn[3];
        double DEN = redd[0] + redd[1] + redd[2] + redd[3];
        double mu = NUM / DEN;
        double r = (double)ws[OFF_SUMM2] - 2.0 * mu * (double)ws[OFF_SUMMT + b]
                 + mu * mu * (double)ws[OFF_SUMTT + b];
        float mx = ws[OFF_MAXM];  // float bits written via uint atomicMax
        double norm = 1048576.0 * (double)mx * (double)mx;
        atomicAdd(out, (float)(sqrt(r / norm) / 8.0));
    }
}

extern "C" void kernel_launch(void* const* d_in, const int* in_sizes, int n_in,
                              void* d_out, int out_size, void* d_ws, size_t ws_size,
                              hipStream_t stream) {
    const float* pred = (const float*)d_in[0];   // [8, 2048]
    const float* M = (const float*)d_in[2];      // [1024, 1024]
    float* ws = (float*)d_ws;
    float* out = (float*)d_out;

    hipMemsetAsync(ws + ZERO_START, 0, (size_t)(WS_END - ZERO_START) * sizeof(float), stream);
    hipMemsetAsync(out, 0, sizeof(float), stream);
    k_init<<<N + 1, T_, 0, stream>>>(M, ws);
    dim3 grid(N, B_);
    k_row<<<grid, T_, 0, stream>>>(pred, M, ws);
    k_final<<<B_, T_, 0, stream>>>(ws, out);
}

// Round 3
// 106.011 us; speedup vs baseline: 2.9556x; 2.2410x over previous
//
#include <hip/hip_runtime.h>
#include <math.h>

#define N 1024
#define B_ 8
#define T_ 256
#define R_ 8        // rows per block
#define NREP 4

// ws layout (float index)
#define OFF_SF      0        // 1024 x float2 (interleaved)          [0, 2048)
#define OFF_TW      2048     // 4 stages x 256 x 8 floats            [2048, 10240)
#define OFF_ROWSUM  10240    // 8 x 1024                             [10240, 18432)
#define ZERO_START  18432
#define OFF_COLSUMM 18432    // 1024
#define OFF_SUMM2   19456
#define OFF_MAXM    19457
#define OFF_SUMMT   19464    // 8
#define OFF_SUMTT   19472    // 8
#define OFF_COLT    20480    // 8 batches x NREP x 1024              [20480, 53248)
#define WS_END      (OFF_COLT + B_ * NREP * N)

// per-transition LDS swizzles (bijective XOR of high addr bits into bank bits)
#define S1(a) ((a) ^ (((a) >> 2) & 0x10))
#define S2(a) ((a) ^ (((a) >> 3) & 0x0C))
#define S3(a) ((a) ^ (((a) >> 5) & 0x07))
#define S4(a) ((a) ^ (((a) >> 5) & 0x07))

__device__ __forceinline__ float wave_sum(float v) {
    #pragma unroll
    for (int o = 32; o > 0; o >>= 1) v += __shfl_down(v, o, 64);
    return v;
}
__device__ __forceinline__ float wave_max(float v) {
    #pragma unroll
    for (int o = 32; o > 0; o >>= 1) v = fmaxf(v, __shfl_down(v, o, 64));
    return v;
}

__device__ __forceinline__ void load_tw(float tw[6], const float* __restrict__ p) {
    float4 v = *(const float4*)p;
    float2 w = *(const float2*)(p + 4);
    tw[0] = v.x; tw[1] = v.y; tw[2] = v.z; tw[3] = v.w; tw[4] = w.x; tw[5] = w.y;
}

// forward radix-4 DIF butterfly + twiddles (W^pos, W^2pos, W^3pos), in place
__device__ __forceinline__ void bfly4(float xr[4], float xi[4], const float tw[6]) {
    float t0r = xr[0] + xr[2], t0i = xi[0] + xi[2];
    float t1r = xr[0] - xr[2], t1i = xi[0] - xi[2];
    float t2r = xr[1] + xr[3], t2i = xi[1] + xi[3];
    float t3r = xr[1] - xr[3], t3i = xi[1] - xi[3];
    float y1r = t1r + t3i, y1i = t1i - t3r;
    float y2r = t0r - t2r, y2i = t0i - t2i;
    float y3r = t1r - t3i, y3i = t1i + t3r;
    xr[0] = t0r + t2r;            xi[0] = t0i + t2i;
    xr[1] = y1r * tw[0] - y1i * tw[1]; xi[1] = y1r * tw[1] + y1i * tw[0];
    xr[2] = y2r * tw[2] - y2i * tw[3]; xi[2] = y2r * tw[3] + y2i * tw[2];
    xr[3] = y3r * tw[4] - y3i * tw[5]; xi[3] = y3r * tw[5] + y3i * tw[4];
}

// sf + twiddle tables: 4 blocks x 256 threads, one entry each
__global__ __launch_bounds__(T_) void k_prep(float* ws) {
    const int e = blockIdx.x * T_ + threadIdx.x;   // 0..1023
    {
        double ang = -2.0 * 337.927 * 1.5 * (double)(e - 512);
        double s, c;
        sincos(ang, &s, &c);
        ws[OFF_SF + 2 * e] = (float)c;
        ws[OFF_SF + 2 * e + 1] = (float)s;
    }
    {
        int s = e >> 8, tt = e & 255;
        int h = 256 >> (2 * s);
        int pos = tt & (h - 1);
        int step = 1 << (2 * s);
        double a1 = -2.0 * M_PI * (double)(pos * step) / 1024.0;
        double s1, c1, s2, c2, s3, c3;
        sincos(a1, &s1, &c1);
        sincos(2.0 * a1, &s2, &c2);
        sincos(3.0 * a1, &s3, &c3);
        float* p = ws + OFF_TW + e * 8;
        p[0] = (float)c1; p[1] = (float)s1;
        p[2] = (float)c2; p[3] = (float)s2;
        p[4] = (float)c3; p[5] = (float)s3;
        p[6] = 0.f; p[7] = 0.f;
    }
}

// M stats: 64 blocks x 16 rows, colsums accumulated in registers -> 64K atomics
__global__ __launch_bounds__(T_) void k_mstats(const float* __restrict__ M, float* ws) {
    const int t = threadIdx.x;
    const int r0 = blockIdx.x * 16;
    float cs[4] = {0.f, 0.f, 0.f, 0.f};
    float sq = 0.f, mx = 0.f;
    for (int r = 0; r < 16; ++r) {
        const float* row = M + (size_t)(r0 + r) * N;
        #pragma unroll
        for (int q = 0; q < 4; ++q) {
            float v = row[t + T_ * q];
            cs[q] += v;
            sq += v * v;
            mx = fmaxf(mx, v);
        }
    }
    #pragma unroll
    for (int q = 0; q < 4; ++q) atomicAdd(&ws[OFF_COLSUMM + t + T_ * q], cs[q]);
    sq = wave_sum(sq);
    mx = wave_max(mx);
    __shared__ float rs_[4], rm_[4];
    int wid = t >> 6, lane = t & 63;
    if (lane == 0) { rs_[wid] = sq; rm_[wid] = mx; }
    __syncthreads();
    if (t == 0) {
        atomicAdd(&ws[OFF_SUMM2], rs_[0] + rs_[1] + rs_[2] + rs_[3]);
        float X = fmaxf(fmaxf(rm_[0], rm_[1]), fmaxf(rm_[2], rm_[3]));
        atomicMax((unsigned int*)ws + OFF_MAXM, __float_as_uint(X));
    }
}

// One block per (8 delay rows, batch b). Column sums in LDS across rows,
// one global atomic per column per block at the end.
__global__ __launch_bounds__(T_, 4) void k_row(const float* __restrict__ pred,
                                               const float* __restrict__ M,
                                               float* __restrict__ ws) {
    __shared__ float Yr[N], Yi[N];
    __shared__ float Ar[N], Ai[N], Br[N], Bi[N];
    __shared__ float colA[N];
    __shared__ float red[3][4];
    const int t = threadIdx.x;
    const int m0 = blockIdx.x * R_;
    const int b = blockIdx.y;
    const int wid = t >> 6, lane = t & 63;

    // stage y into LDS + zero column accumulator
    {
        const float* pr = pred + (size_t)b * 2 * N;
        #pragma unroll
        for (int q = 0; q < 4; ++q) {
            int j = t + T_ * q;
            Yr[j] = pr[j];
            Yi[j] = pr[N + j];
            colA[j] = 0.f;
        }
    }
    __syncthreads();

    float mtacc = 0.f, ttacc = 0.f;
    float xr[4], xi[4], tw[6];

    for (int r = 0; r < R_; ++r) {
        const int m = m0 + r;

        // product + stage 0 (h=256), in registers
        {
            const float2* sf2 = (const float2*)(ws + OFF_SF);
            #pragma unroll
            for (int q = 0; q < 4; ++q) {
                int j = t + T_ * q;
                int s = (j - m + 512) & (N - 1);
                float ar = Yr[j], ai = Yi[j];
                float br = Yr[s], bi = Yi[s];
                float2 sv = sf2[j];
                float p_r = ar * br - ai * bi;
                float p_i = ar * bi + ai * br;
                xr[q] = p_r * sv.x - p_i * sv.y;
                xi[q] = p_r * sv.y + p_i * sv.x;
            }
            load_tw(tw, ws + OFF_TW + (size_t)t * 8);
            bfly4(xr, xi, tw);
            #pragma unroll
            for (int q = 0; q < 4; ++q) { int a = t + 256 * q; Ar[a] = xr[q]; Ai[a] = xi[q]; }
        }
        __syncthreads();

        // stage 1 (h=64): read A, write B (S1)
        {
            int base = ((t >> 6) << 8) | (t & 63);
            #pragma unroll
            for (int q = 0; q < 4; ++q) { int a = base + (q << 6); xr[q] = Ar[a]; xi[q] = Ai[a]; }
            load_tw(tw, ws + OFF_TW + (size_t)(256 + t) * 8);
            bfly4(xr, xi, tw);
            #pragma unroll
            for (int q = 0; q < 4; ++q) { int a = S1(base + (q << 6)); Br[a] = xr[q]; Bi[a] = xi[q]; }
        }
        __syncthreads();

        // stage 2 (h=16): read B (S1), write A (S2)
        {
            int base = ((t >> 4) << 6) | (t & 15);
            #pragma unroll
            for (int q = 0; q < 4; ++q) { int a = S1(base + (q << 4)); xr[q] = Br[a]; xi[q] = Bi[a]; }
            load_tw(tw, ws + OFF_TW + (size_t)(512 + t) * 8);
            bfly4(xr, xi, tw);
            #pragma unroll
            for (int q = 0; q < 4; ++q) { int a = S2(base + (q << 4)); Ar[a] = xr[q]; Ai[a] = xi[q]; }
        }
        __syncthreads();

        // stage 3 (h=4): read A (S2), write B (S3)
        {
            int base = ((t >> 2) << 4) | (t & 3);
            #pragma unroll
            for (int q = 0; q < 4; ++q) { int a = S2(base + (q << 2)); xr[q] = Ar[a]; xi[q] = Ai[a]; }
            load_tw(tw, ws + OFF_TW + (size_t)(768 + t) * 8);
            bfly4(xr, xi, tw);
            #pragma unroll
            for (int q = 0; q < 4; ++q) { int a = S3(base + (q << 2)); Br[a] = xr[q]; Bi[a] = xi[q]; }
        }
        __syncthreads();

        // stage 4 (h=1, W=1): read B (S3), magnitudes -> scatter to A (S4)
        {
            int base = t << 2;
            #pragma unroll
            for (int q = 0; q < 4; ++q) { int a = S3(base + q); xr[q] = Br[a]; xi[q] = Bi[a]; }
            float t0r = xr[0] + xr[2], t0i = xi[0] + xi[2];
            float t1r = xr[0] - xr[2], t1i = xi[0] - xi[2];
            float t2r = xr[1] + xr[3], t2i = xi[1] + xi[3];
            float t3r = xr[1] - xr[3], t3i = xi[1] - xi[3];
            float yr[4], yi[4];
            yr[0] = t0r + t2r; yi[0] = t0i + t2i;
            yr[1] = t1r + t3i; yi[1] = t1i - t3r;
            yr[2] = t0r - t2r; yi[2] = t0i - t2i;
            yr[3] = t1r - t3i; yi[3] = t1i + t3r;
            int r4t = ((t & 3) << 6) | (((t >> 2) & 3) << 4) | (((t >> 4) & 3) << 2) | ((t >> 6) & 3);
            #pragma unroll
            for (int q = 0; q < 4; ++q) {
                int c = ((q << 8) | r4t) ^ 512;
                Ar[S4(c)] = 1.5f * sqrtf(yr[q] * yr[q] + yi[q] * yi[q]);
            }
        }
        __syncthreads();

        // per-row: rowsum reduce; per-thread: colA accumulate, MT/TT partials
        {
            const float* Mrow = M + (size_t)m * N;
            float rs = 0.f;
            #pragma unroll
            for (int q = 0; q < 4; ++q) {
                int cc = t + 256 * q;
                float v = Ar[S4(cc)];
                rs += v;
                ttacc += v * v;
                mtacc += Mrow[cc] * v;
                colA[cc] += v;
            }
            rs = wave_sum(rs);
            if (lane == 0) red[0][wid] = rs;
            __syncthreads();   // red ready; also guards Ar reads vs next row's writes
            if (t == 0) {
                ws[OFF_ROWSUM + b * N + m] = red[0][0] + red[0][1] + red[0][2] + red[0][3];
            }
        }
    }

    // block epilogue: flush colA (1 atomic/column) + reduced MT/TT
    {
        float* colT = ws + OFF_COLT + (size_t)(b * NREP + (blockIdx.x & (NREP - 1))) * N;
        #pragma unroll
        for (int q = 0; q < 4; ++q) {
            int cc = t + 256 * q;
            atomicAdd(&colT[cc], colA[cc]);
        }
        float mt = wave_sum(mtacc);
        float tt2 = wave_sum(ttacc);
        if (lane == 0) { red[1][wid] = mt; red[2][wid] = tt2; }
        __syncthreads();
        if (t == 0) {
            atomicAdd(&ws[OFF_SUMMT + b], red[1][0] + red[1][1] + red[1][2] + red[1][3]);
            atomicAdd(&ws[OFF_SUMTT + b], red[2][0] + red[2][1] + red[2][2] + red[2][3]);
        }
    }
}

__global__ __launch_bounds__(T_) void k_final(float* ws, float* out) {
    __shared__ double redn[4], redd[4];
    const int b = blockIdx.x;
    const int t = threadIdx.x;
    const int wid = t >> 6, lane = t & 63;
    const float* rowsum = ws + OFF_ROWSUM + (size_t)b * N;
    double num = 0.0, den = 0.0;
    #pragma unroll
    for (int q = 0; q < 4; ++q) {
        int j = t + 256 * q;
        double r = (double)rowsum[j];
        float ct = 0.f;
        #pragma unroll
        for (int rep = 0; rep < NREP; ++rep)
            ct += ws[OFF_COLT + (size_t)(b * NREP + rep) * N + j];
        num += (double)ws[OFF_COLSUMM + j] * r;
        den += (double)ct * r;
    }
    #pragma unroll
    for (int o = 32; o > 0; o >>= 1) {
        num += __shfl_down(num, o, 64);
        den += __shfl_down(den, o, 64);
    }
    if (lane == 0) { redn[wid] = num; redd[wid] = den; }
    __syncthreads();
    if (t == 0) {
        double NUM = redn[0] + redn[1] + redn[2] + redn[3];
        double DEN = redd[0] + redd[1] + redd[2] + redd[3];
        double mu = NUM / DEN;
        double r = (double)ws[OFF_SUMM2] - 2.0 * mu * (double)ws[OFF_SUMMT + b]
                 + mu * mu * (double)ws[OFF_SUMTT + b];
        float mx = ws[OFF_MAXM];  // float bits written via uint atomicMax
        double norm = 1048576.0 * (double)mx * (double)mx;
        atomicAdd(out, (float)(sqrt(r / norm) / 8.0));
    }
}

extern "C" void kernel_launch(void* const* d_in, const int* in_sizes, int n_in,
                              void* d_out, int out_size, void* d_ws, size_t ws_size,
                              hipStream_t stream) {
    const float* pred = (const float*)d_in[0];   // [8, 2048]
    const float* M = (const float*)d_in[2];      // [1024, 1024]
    float* ws = (float*)d_ws;
    float* out = (float*)d_out;

    hipMemsetAsync(ws + ZERO_START, 0, (size_t)(WS_END - ZERO_START) * sizeof(float), stream);
    hipMemsetAsync(out, 0, sizeof(float), stream);
    k_prep<<<4, T_, 0, stream>>>(ws);
    k_mstats<<<64, T_, 0, stream>>>(M, ws);
    dim3 grid(N / R_, B_);
    k_row<<<grid, T_, 0, stream>>>(pred, M, ws);
    k_final<<<B_, T_, 0, stream>>>(ws, out);
}

// Round 4
// 105.336 us; speedup vs baseline: 2.9746x; 1.0064x over previous
//
#include <hip/hip_runtime.h>
#include <math.h>

#define N 1024
#define B_ 8
#define T_ 256
#define R_ 4        // rows per block (distinct delays)
#define NREP 4
#define GX 129      // blocks 0..127: m=4*blk..4*blk+3 (0..511); block 128: m=512

// ws layout (float index)
#define OFF_SF      0        // 1024 x float2 (interleaved)          [0, 2048)
#define OFF_TW      2048     // 4 stages x 256 x 8 floats            [2048, 10240)
#define OFF_ROWSUM  10240    // 8 x 1024                             [10240, 18432)
#define ZERO_START  18432
#define OFF_COLSUMM 18432    // 1024
#define OFF_SUMM2   19456
#define OFF_MAXM    19457
#define OFF_SUMMT   19464    // 8
#define OFF_SUMTT   19472    // 8
#define OFF_COLT    20480    // 8 batches x NREP x 1024              [20480, 53248)
#define WS_END      (OFF_COLT + B_ * NREP * N)

// per-transition LDS swizzles (bijective XOR of high addr bits into bank bits)
#define S1(a) ((a) ^ (((a) >> 2) & 0x10))
#define S2(a) ((a) ^ (((a) >> 3) & 0x0C))
#define S3(a) ((a) ^ (((a) >> 5) & 0x07))
#define S4(a) ((a) ^ (((a) >> 5) & 0x07))

__device__ __forceinline__ float wave_sum(float v) {
    #pragma unroll
    for (int o = 32; o > 0; o >>= 1) v += __shfl_down(v, o, 64);
    return v;
}
__device__ __forceinline__ float wave_max(float v) {
    #pragma unroll
    for (int o = 32; o > 0; o >>= 1) v = fmaxf(v, __shfl_down(v, o, 64));
    return v;
}

__device__ __forceinline__ void load_tw(float tw[6], const float* __restrict__ p) {
    float4 v = *(const float4*)p;
    float2 w = *(const float2*)(p + 4);
    tw[0] = v.x; tw[1] = v.y; tw[2] = v.z; tw[3] = v.w; tw[4] = w.x; tw[5] = w.y;
}

// forward radix-4 DIF butterfly + twiddles (W^pos, W^2pos, W^3pos), in place
__device__ __forceinline__ void bfly4(float xr[4], float xi[4], const float tw[6]) {
    float t0r = xr[0] + xr[2], t0i = xi[0] + xi[2];
    float t1r = xr[0] - xr[2], t1i = xi[0] - xi[2];
    float t2r = xr[1] + xr[3], t2i = xi[1] + xi[3];
    float t3r = xr[1] - xr[3], t3i = xi[1] - xi[3];
    float y1r = t1r + t3i, y1i = t1i - t3r;
    float y2r = t0r - t2r, y2i = t0i - t2i;
    float y3r = t1r - t3i, y3i = t1i + t3r;
    xr[0] = t0r + t2r;            xi[0] = t0i + t2i;
    xr[1] = y1r * tw[0] - y1i * tw[1]; xi[1] = y1r * tw[1] + y1i * tw[0];
    xr[2] = y2r * tw[2] - y2i * tw[3]; xi[2] = y2r * tw[3] + y2i * tw[2];
    xr[3] = y3r * tw[4] - y3i * tw[5]; xi[3] = y3r * tw[5] + y3i * tw[4];
}

// sf + twiddle tables + zero accumulators + zero out: 4 blocks x 256 threads
__global__ __launch_bounds__(T_) void k_prep(float* ws, float* out) {
    const int e = blockIdx.x * T_ + threadIdx.x;   // 0..1023
    {
        double ang = -2.0 * 337.927 * 1.5 * (double)(e - 512);
        double s, c;
        sincos(ang, &s, &c);
        ws[OFF_SF + 2 * e] = (float)c;
        ws[OFF_SF + 2 * e + 1] = (float)s;
    }
    {
        int s = e >> 8, tt = e & 255;
        int h = 256 >> (2 * s);
        int pos = tt & (h - 1);
        int step = 1 << (2 * s);
        double a1 = -2.0 * M_PI * (double)(pos * step) / 1024.0;
        double s1, c1, s2, c2, s3, c3;
        sincos(a1, &s1, &c1);
        sincos(2.0 * a1, &s2, &c2);
        sincos(3.0 * a1, &s3, &c3);
        float* p = ws + OFF_TW + e * 8;
        p[0] = (float)c1; p[1] = (float)s1;
        p[2] = (float)c2; p[3] = (float)s2;
        p[4] = (float)c3; p[5] = (float)s3;
        p[6] = 0.f; p[7] = 0.f;
    }
    for (int j = ZERO_START + e; j < WS_END; j += 4 * T_) ws[j] = 0.f;
    if (e == 0) out[0] = 0.f;
}

// One block per (R_ delay rows, batch b), exploiting T[m] == T[1024-m].
// b==0 blocks additionally accumulate M column-sums / sum(M^2) / max(M).
__global__ __launch_bounds__(T_, 4) void k_row(const float* __restrict__ pred,
                                               const float* __restrict__ M,
                                               float* __restrict__ ws) {
    __shared__ float Yr[N], Yi[N];
    __shared__ float Ar[N], Ai[N], Br[N], Bi[N];
    __shared__ float colA[N], colM[N];
    __shared__ float red[5][4];
    const int t = threadIdx.x;
    const int blk = blockIdx.x;
    const int b = blockIdx.y;
    const int nr = (blk == GX - 1) ? 1 : R_;
    const int m0 = blk * R_;
    const int wid = t >> 6, lane = t & 63;

    // stage y into LDS + zero column accumulators
    {
        const float* pr = pred + (size_t)b * 2 * N;
        #pragma unroll
        for (int q = 0; q < 4; ++q) {
            int j = t + T_ * q;
            Yr[j] = pr[j];
            Yi[j] = pr[N + j];
            colA[j] = 0.f;
            colM[j] = 0.f;
        }
    }
    __syncthreads();

    float mtacc = 0.f, ttacc = 0.f, sqacc = 0.f, mxacc = 0.f;
    float xr[4], xi[4], tw[6];

    for (int r = 0; r < nr; ++r) {
        const int m = m0 + r;
        const int mm = (N - m) & (N - 1);   // mirror row; == m for m=0,512
        const float w = (mm == m) ? 1.f : 2.f;

        // product + stage 0 (h=256), in registers
        {
            const float2* sf2 = (const float2*)(ws + OFF_SF);
            #pragma unroll
            for (int q = 0; q < 4; ++q) {
                int j = t + T_ * q;
                int s = (j - m + 512) & (N - 1);
                float ar = Yr[j], ai = Yi[j];
                float br = Yr[s], bi = Yi[s];
                float2 sv = sf2[j];
                float p_r = ar * br - ai * bi;
                float p_i = ar * bi + ai * br;
                xr[q] = p_r * sv.x - p_i * sv.y;
                xi[q] = p_r * sv.y + p_i * sv.x;
            }
            load_tw(tw, ws + OFF_TW + (size_t)t * 8);
            bfly4(xr, xi, tw);
            #pragma unroll
            for (int q = 0; q < 4; ++q) { int a = t + 256 * q; Ar[a] = xr[q]; Ai[a] = xi[q]; }
        }
        __syncthreads();

        // stage 1 (h=64): read A, write B (S1)
        {
            int base = ((t >> 6) << 8) | (t & 63);
            #pragma unroll
            for (int q = 0; q < 4; ++q) { int a = base + (q << 6); xr[q] = Ar[a]; xi[q] = Ai[a]; }
            load_tw(tw, ws + OFF_TW + (size_t)(256 + t) * 8);
            bfly4(xr, xi, tw);
            #pragma unroll
            for (int q = 0; q < 4; ++q) { int a = S1(base + (q << 6)); Br[a] = xr[q]; Bi[a] = xi[q]; }
        }
        __syncthreads();

        // stage 2 (h=16): read B (S1), write A (S2)
        {
            int base = ((t >> 4) << 6) | (t & 15);
            #pragma unroll
            for (int q = 0; q < 4; ++q) { int a = S1(base + (q << 4)); xr[q] = Br[a]; xi[q] = Bi[a]; }
            load_tw(tw, ws + OFF_TW + (size_t)(512 + t) * 8);
            bfly4(xr, xi, tw);
            #pragma unroll
            for (int q = 0; q < 4; ++q) { int a = S2(base + (q << 4)); Ar[a] = xr[q]; Ai[a] = xi[q]; }
        }
        __syncthreads();

        // stage 3 (h=4): read A (S2), write B (S3)
        {
            int base = ((t >> 2) << 4) | (t & 3);
            #pragma unroll
            for (int q = 0; q < 4; ++q) { int a = S2(base + (q << 2)); xr[q] = Ar[a]; xi[q] = Ai[a]; }
            load_tw(tw, ws + OFF_TW + (size_t)(768 + t) * 8);
            bfly4(xr, xi, tw);
            #pragma unroll
            for (int q = 0; q < 4; ++q) { int a = S3(base + (q << 2)); Br[a] = xr[q]; Bi[a] = xi[q]; }
        }
        __syncthreads();

        // stage 4 (h=1, W=1): read B (S3), magnitudes -> scatter to A (S4)
        {
            int base = t << 2;
            #pragma unroll
            for (int q = 0; q < 4; ++q) { int a = S3(base + q); xr[q] = Br[a]; xi[q] = Bi[a]; }
            float t0r = xr[0] + xr[2], t0i = xi[0] + xi[2];
            float t1r = xr[0] - xr[2], t1i = xi[0] - xi[2];
            float t2r = xr[1] + xr[3], t2i = xi[1] + xi[3];
            float t3r = xr[1] - xr[3], t3i = xi[1] - xi[3];
            float yr[4], yi[4];
            yr[0] = t0r + t2r; yi[0] = t0i + t2i;
            yr[1] = t1r + t3i; yi[1] = t1i - t3r;
            yr[2] = t0r - t2r; yi[2] = t0i - t2i;
            yr[3] = t1r - t3i; yi[3] = t1i + t3r;
            int r4t = ((t & 3) << 6) | (((t >> 2) & 3) << 4) | (((t >> 4) & 3) << 2) | ((t >> 6) & 3);
            #pragma unroll
            for (int q = 0; q < 4; ++q) {
                int c = ((q << 8) | r4t) ^ 512;
                Ar[S4(c)] = 1.5f * sqrtf(yr[q] * yr[q] + yi[q] * yi[q]);
            }
        }
        __syncthreads();

        // per-row: rowsum reduce; per-thread: colA/colM accumulate, MT/TT/M-stat partials
        {
            const float* Mrow = M + (size_t)m * N;
            const float* Mrow2 = M + (size_t)mm * N;
            float rs = 0.f;
            #pragma unroll
            for (int q = 0; q < 4; ++q) {
                int cc = t + 256 * q;
                float v = Ar[S4(cc)];
                rs += v;
                ttacc += w * v * v;
                float m1 = Mrow[cc];
                float msum = m1;
                if (mm != m) msum += Mrow2[cc];
                mtacc += msum * v;
                colA[cc] += w * v;
                if (b == 0) {
                    colM[cc] += msum;
                    sqacc += m1 * m1;
                    mxacc = fmaxf(mxacc, m1);
                    if (mm != m) {
                        float m2 = msum - m1;
                        sqacc += m2 * m2;
                        mxacc = fmaxf(mxacc, m2);
                    }
                }
            }
            rs = wave_sum(rs);
            if (lane == 0) red[0][wid] = rs;
            __syncthreads();   // red ready; also guards Ar reads vs next row's writes
            if (t == 0) {
                float R = red[0][0] + red[0][1] + red[0][2] + red[0][3];
                ws[OFF_ROWSUM + b * N + m] = R;
                if (mm != m) ws[OFF_ROWSUM + b * N + mm] = R;
            }
        }
    }

    // block epilogue: flush colA (1 atomic/column), colM (b==0), reduced MT/TT/M-stats
    {
        float* colT = ws + OFF_COLT + (size_t)(b * NREP + (blk & (NREP - 1))) * N;
        #pragma unroll
        for (int q = 0; q < 4; ++q) {
            int cc = t + 256 * q;
            atomicAdd(&colT[cc], colA[cc]);
        }
        if (b == 0) {
            #pragma unroll
            for (int q = 0; q < 4; ++q) {
                int cc = t + 256 * q;
                atomicAdd(&ws[OFF_COLSUMM + cc], colM[cc]);
            }
        }
        float mt = wave_sum(mtacc);
        float tt2 = wave_sum(ttacc);
        if (lane == 0) { red[1][wid] = mt; red[2][wid] = tt2; }
        if (b == 0) {
            float sq = wave_sum(sqacc);
            float mx = wave_max(mxacc);
            if (lane == 0) { red[3][wid] = sq; red[4][wid] = mx; }
        }
        __syncthreads();
        if (t == 0) {
            atomicAdd(&ws[OFF_SUMMT + b], red[1][0] + red[1][1] + red[1][2] + red[1][3]);
            atomicAdd(&ws[OFF_SUMTT + b], red[2][0] + red[2][1] + red[2][2] + red[2][3]);
            if (b == 0) {
                atomicAdd(&ws[OFF_SUMM2], red[3][0] + red[3][1] + red[3][2] + red[3][3]);
                float X = fmaxf(fmaxf(red[4][0], red[4][1]), fmaxf(red[4][2], red[4][3]));
                atomicMax((unsigned int*)ws + OFF_MAXM, __float_as_uint(X));
            }
        }
    }
}

__global__ __launch_bounds__(T_) void k_final(float* ws, float* out) {
    __shared__ double redn[4], redd[4];
    const int b = blockIdx.x;
    const int t = threadIdx.x;
    const int wid = t >> 6, lane = t & 63;
    const float* rowsum = ws + OFF_ROWSUM + (size_t)b * N;
    double num = 0.0, den = 0.0;
    #pragma unroll
    for (int q = 0; q < 4; ++q) {
        int j = t + 256 * q;
        double r = (double)rowsum[j];
        float ct = 0.f;
        #pragma unroll
        for (int rep = 0; rep < NREP; ++rep)
            ct += ws[OFF_COLT + (size_t)(b * NREP + rep) * N + j];
        num += (double)ws[OFF_COLSUMM + j] * r;
        den += (double)ct * r;
    }
    #pragma unroll
    for (int o = 32; o > 0; o >>= 1) {
        num += __shfl_down(num, o, 64);
        den += __shfl_down(den, o, 64);
    }
    if (lane == 0) { redn[wid] = num; redd[wid] = den; }
    __syncthreads();
    if (t == 0) {
        double NUM = redn[0] + redn[1] + redn[2] + redn[3];
        double DEN = redd[0] + redd[1] + redd[2] + redd[3];
        double mu = NUM / DEN;
        double r = (double)ws[OFF_SUMM2] - 2.0 * mu * (double)ws[OFF_SUMMT + b]
                 + mu * mu * (double)ws[OFF_SUMTT + b];
        float mx = ws[OFF_MAXM];  // float bits written via uint atomicMax
        double norm = 1048576.0 * (double)mx * (double)mx;
        atomicAdd(out, (float)(sqrt(r / norm) / 8.0));
    }
}

extern "C" void kernel_launch(void* const* d_in, const int* in_sizes, int n_in,
                              void* d_out, int out_size, void* d_ws, size_t ws_size,
                              hipStream_t stream) {
    const float* pred = (const float*)d_in[0];   // [8, 2048]
    const float* M = (const float*)d_in[2];      // [1024, 1024]
    float* ws = (float*)d_ws;
    float* out = (float*)d_out;

    k_prep<<<4, T_, 0, stream>>>(ws, out);
    dim3 grid(GX, B_);
    k_row<<<grid, T_, 0, stream>>>(pred, M, ws);
    k_final<<<B_, T_, 0, stream>>>(ws, out);
}

// Round 5
// 100.949 us; speedup vs baseline: 3.1038x; 1.0435x over previous
//
#include <hip/hip_runtime.h>
#include <math.h>

#define N 1024
#define B_ 8
#define T_ 256
#define R_ 4        // delay rows per FFT block
#define NREP 4
#define GX 129      // blocks 0..127: m=4*blk..4*blk+3 (0..511); block 128: m=512

// ws layout (float index)
#define OFF_SF      0        // 1024 x float2 (interleaved)          [0, 2048)
#define OFF_TW      2048     // 4 stages x 256 x 8 floats            [2048, 10240)
#define OFF_ROWSUM  10240    // 8 x 1024                             [10240, 18432)
#define ZERO_START  18432
#define OFF_COLSUMM 18432    // 1024
#define OFF_SUMM2   19456
#define OFF_MAXM    19457
#define OFF_SUMMT   19464    // 8
#define OFF_SUMTT   19472    // 8
#define OFF_COLT    20480    // 8 batches x NREP x 1024              [20480, 53248)
#define WS_END      (OFF_COLT + B_ * NREP * N)

// per-transition LDS swizzles (bijective XOR of high addr bits into bank bits)
#define S1(a) ((a) ^ (((a) >> 2) & 0x10))
#define S2(a) ((a) ^ (((a) >> 3) & 0x0C))
#define S3(a) ((a) ^ (((a) >> 5) & 0x07))
#define S4(a) ((a) ^ (((a) >> 5) & 0x07))

__device__ __forceinline__ float wave_sum(float v) {
    #pragma unroll
    for (int o = 32; o > 0; o >>= 1) v += __shfl_down(v, o, 64);
    return v;
}
__device__ __forceinline__ float wave_max(float v) {
    #pragma unroll
    for (int o = 32; o > 0; o >>= 1) v = fmaxf(v, __shfl_down(v, o, 64));
    return v;
}

__device__ __forceinline__ void load_tw(float tw[6], const float* __restrict__ p) {
    float4 v = *(const float4*)p;
    float2 w = *(const float2*)(p + 4);
    tw[0] = v.x; tw[1] = v.y; tw[2] = v.z; tw[3] = v.w; tw[4] = w.x; tw[5] = w.y;
}

// forward radix-4 DIF butterfly + twiddles (W^pos, W^2pos, W^3pos), in place
__device__ __forceinline__ void bfly4(float xr[4], float xi[4], const float tw[6]) {
    float t0r = xr[0] + xr[2], t0i = xi[0] + xi[2];
    float t1r = xr[0] - xr[2], t1i = xi[0] - xi[2];
    float t2r = xr[1] + xr[3], t2i = xi[1] + xi[3];
    float t3r = xr[1] - xr[3], t3i = xi[1] - xi[3];
    float y1r = t1r + t3i, y1i = t1i - t3r;
    float y2r = t0r - t2r, y2i = t0i - t2i;
    float y3r = t1r - t3i, y3i = t1i + t3r;
    xr[0] = t0r + t2r;            xi[0] = t0i + t2i;
    xr[1] = y1r * tw[0] - y1i * tw[1]; xi[1] = y1r * tw[1] + y1i * tw[0];
    xr[2] = y2r * tw[2] - y2i * tw[3]; xi[2] = y2r * tw[3] + y2i * tw[2];
    xr[3] = y3r * tw[4] - y3i * tw[5]; xi[3] = y3r * tw[5] + y3i * tw[4];
}

// sf + twiddle tables + zero accumulators + zero out: 4 blocks x 256 threads
__global__ __launch_bounds__(T_) void k_prep(float* ws, float* out) {
    const int e = blockIdx.x * T_ + threadIdx.x;   // 0..1023
    {
        double ang = -2.0 * 337.927 * 1.5 * (double)(e - 512);
        double s, c;
        sincos(ang, &s, &c);
        ws[OFF_SF + 2 * e] = (float)c;
        ws[OFF_SF + 2 * e + 1] = (float)s;
    }
    {
        int s = e >> 8, tt = e & 255;
        int h = 256 >> (2 * s);
        int pos = tt & (h - 1);
        int step = 1 << (2 * s);
        double a1 = -2.0 * M_PI * (double)(pos * step) / 1024.0;
        double s1, c1, s2, c2, s3, c3;
        sincos(a1, &s1, &c1);
        sincos(2.0 * a1, &s2, &c2);
        sincos(3.0 * a1, &s3, &c3);
        float* p = ws + OFF_TW + e * 8;
        p[0] = (float)c1; p[1] = (float)s1;
        p[2] = (float)c2; p[3] = (float)s2;
        p[4] = (float)c3; p[5] = (float)s3;
        p[6] = 0.f; p[7] = 0.f;
    }
    for (int j = ZERO_START + e; j < WS_END; j += 4 * T_) ws[j] = 0.f;
    if (e == 0) out[0] = 0.f;
}

// grid (GX, B_+1):
//   y < B_ : FFT blocks — R_ delay rows of batch y, exploiting T[m]==T[1024-m]
//   y == B_: blocks 0..63 compute M stats (colsumM / sumM2 / maxM), rest exit
__global__ __launch_bounds__(T_, 6) void k_row(const float* __restrict__ pred,
                                               const float* __restrict__ M,
                                               float* __restrict__ ws) {
    __shared__ float Yr[N], Yi[N];
    __shared__ float Ar[N], Ai[N], Br[N], Bi[N];
    __shared__ float colA[N];
    __shared__ float red[R_ + 2][4];
    const int t = threadIdx.x;
    const int blk = blockIdx.x;
    const int b = blockIdx.y;
    const int wid = t >> 6, lane = t & 63;

    if (b == B_) {
        // ---- M-stats slice (runs concurrently with the FFT blocks) ----
        if (blk >= 64) return;
        const int r0 = blk * 16;
        float cs[4] = {0.f, 0.f, 0.f, 0.f};
        float sq = 0.f, mx = 0.f;
        for (int r = 0; r < 16; ++r) {
            const float* row = M + (size_t)(r0 + r) * N;
            #pragma unroll
            for (int q = 0; q < 4; ++q) {
                float v = row[t + T_ * q];
                cs[q] += v;
                sq += v * v;
                mx = fmaxf(mx, v);
            }
        }
        #pragma unroll
        for (int q = 0; q < 4; ++q) atomicAdd(&ws[OFF_COLSUMM + t + T_ * q], cs[q]);
        sq = wave_sum(sq);
        mx = wave_max(mx);
        if (lane == 0) { red[0][wid] = sq; red[1][wid] = mx; }
        __syncthreads();
        if (t == 0) {
            atomicAdd(&ws[OFF_SUMM2], red[0][0] + red[0][1] + red[0][2] + red[0][3]);
            float X = fmaxf(fmaxf(red[1][0], red[1][1]), fmaxf(red[1][2], red[1][3]));
            atomicMax((unsigned int*)ws + OFF_MAXM, __float_as_uint(X));
        }
        return;
    }

    // ---- FFT slice ----
    const int nr = (blk == GX - 1) ? 1 : R_;
    const int m0 = blk * R_;

    // stage y into LDS + zero column accumulator
    {
        const float* pr = pred + (size_t)b * 2 * N;
        #pragma unroll
        for (int q = 0; q < 4; ++q) {
            int j = t + T_ * q;
            Yr[j] = pr[j];
            Yi[j] = pr[N + j];
            colA[j] = 0.f;
        }
    }

    // twiddles depend only on (t, stage): hoist out of the row loop
    float tw0[6], tw1[6], tw2[6], tw3[6];
    load_tw(tw0, ws + OFF_TW + (size_t)t * 8);
    load_tw(tw1, ws + OFF_TW + (size_t)(256 + t) * 8);
    load_tw(tw2, ws + OFF_TW + (size_t)(512 + t) * 8);
    load_tw(tw3, ws + OFF_TW + (size_t)(768 + t) * 8);
    __syncthreads();

    float mtacc = 0.f, ttacc = 0.f;
    float xr[4], xi[4];

    for (int r = 0; r < nr; ++r) {
        const int m = m0 + r;
        const int mm = (N - m) & (N - 1);   // mirror row; == m for m=0,512
        const float w = (mm == m) ? 1.f : 2.f;

        // product + stage 0 (h=256), in registers
        {
            const float2* sf2 = (const float2*)(ws + OFF_SF);
            #pragma unroll
            for (int q = 0; q < 4; ++q) {
                int j = t + T_ * q;
                int s = (j - m + 512) & (N - 1);
                float ar = Yr[j], ai = Yi[j];
                float br = Yr[s], bi = Yi[s];
                float2 sv = sf2[j];
                float p_r = ar * br - ai * bi;
                float p_i = ar * bi + ai * br;
                xr[q] = p_r * sv.x - p_i * sv.y;
                xi[q] = p_r * sv.y + p_i * sv.x;
            }
            bfly4(xr, xi, tw0);
            #pragma unroll
            for (int q = 0; q < 4; ++q) { int a = t + 256 * q; Ar[a] = xr[q]; Ai[a] = xi[q]; }
        }
        __syncthreads();

        // stage 1 (h=64): read A, write B (S1)
        {
            int base = ((t >> 6) << 8) | (t & 63);
            #pragma unroll
            for (int q = 0; q < 4; ++q) { int a = base + (q << 6); xr[q] = Ar[a]; xi[q] = Ai[a]; }
            bfly4(xr, xi, tw1);
            #pragma unroll
            for (int q = 0; q < 4; ++q) { int a = S1(base + (q << 6)); Br[a] = xr[q]; Bi[a] = xi[q]; }
        }
        __syncthreads();

        // stage 2 (h=16): read B (S1), write A (S2)
        {
            int base = ((t >> 4) << 6) | (t & 15);
            #pragma unroll
            for (int q = 0; q < 4; ++q) { int a = S1(base + (q << 4)); xr[q] = Br[a]; xi[q] = Bi[a]; }
            bfly4(xr, xi, tw2);
            #pragma unroll
            for (int q = 0; q < 4; ++q) { int a = S2(base + (q << 4)); Ar[a] = xr[q]; Ai[a] = xi[q]; }
        }
        __syncthreads();

        // stage 3 (h=4): read A (S2), write B (S3)
        {
            int base = ((t >> 2) << 4) | (t & 3);
            #pragma unroll
            for (int q = 0; q < 4; ++q) { int a = S2(base + (q << 2)); xr[q] = Ar[a]; xi[q] = Ai[a]; }
            bfly4(xr, xi, tw3);
            #pragma unroll
            for (int q = 0; q < 4; ++q) { int a = S3(base + (q << 2)); Br[a] = xr[q]; Bi[a] = xi[q]; }
        }
        __syncthreads();

        // stage 4 (h=1, W=1): read B (S3), magnitudes -> scatter to A (S4)
        {
            int base = t << 2;
            #pragma unroll
            for (int q = 0; q < 4; ++q) { int a = S3(base + q); xr[q] = Br[a]; xi[q] = Bi[a]; }
            float t0r = xr[0] + xr[2], t0i = xi[0] + xi[2];
            float t1r = xr[0] - xr[2], t1i = xi[0] - xi[2];
            float t2r = xr[1] + xr[3], t2i = xi[1] + xi[3];
            float t3r = xr[1] - xr[3], t3i = xi[1] - xi[3];
            float yr[4], yi[4];
            yr[0] = t0r + t2r; yi[0] = t0i + t2i;
            yr[1] = t1r + t3i; yi[1] = t1i - t3r;
            yr[2] = t0r - t2r; yi[2] = t0i - t2i;
            yr[3] = t1r - t3i; yi[3] = t1i + t3r;
            int r4t = ((t & 3) << 6) | (((t >> 2) & 3) << 4) | (((t >> 4) & 3) << 2) | ((t >> 6) & 3);
            #pragma unroll
            for (int q = 0; q < 4; ++q) {
                int c = ((q << 8) | r4t) ^ 512;
                Ar[S4(c)] = 1.5f * sqrtf(yr[q] * yr[q] + yi[q] * yi[q]);
            }
        }
        __syncthreads();

        // per-row reductions; rowsum finalization deferred to epilogue
        {
            const float* Mrow = M + (size_t)m * N;
            const float* Mrow2 = M + (size_t)mm * N;
            float rs = 0.f;
            #pragma unroll
            for (int q = 0; q < 4; ++q) {
                int cc = t + 256 * q;
                float v = Ar[S4(cc)];
                rs += v;
                ttacc += w * v * v;
                float msum = Mrow[cc];
                if (mm != m) msum += Mrow2[cc];
                mtacc += msum * v;
                colA[cc] += w * v;
            }
            rs = wave_sum(rs);
            if (lane == 0) red[r][wid] = rs;
        }
        __syncthreads();   // guards Ar/colA reads vs next row's writes; red[r] published
    }

    // block epilogue: flush colA (1 atomic/column), rowsums, reduced MT/TT
    {
        float* colT = ws + OFF_COLT + (size_t)(b * NREP + (blk & (NREP - 1))) * N;
        #pragma unroll
        for (int q = 0; q < 4; ++q) {
            int cc = t + 256 * q;
            atomicAdd(&colT[cc], colA[cc]);
        }
        float mt = wave_sum(mtacc);
        float tt2 = wave_sum(ttacc);
        if (lane == 0) { red[R_][wid] = mt; red[R_ + 1][wid] = tt2; }
        __syncthreads();
        if (t == 0) {
            for (int r = 0; r < nr; ++r) {
                int m = m0 + r, mm = (N - m) & (N - 1);
                float R = red[r][0] + red[r][1] + red[r][2] + red[r][3];
                ws[OFF_ROWSUM + b * N + m] = R;
                if (mm != m) ws[OFF_ROWSUM + b * N + mm] = R;
            }
            atomicAdd(&ws[OFF_SUMMT + b], red[R_][0] + red[R_][1] + red[R_][2] + red[R_][3]);
            atomicAdd(&ws[OFF_SUMTT + b], red[R_ + 1][0] + red[R_ + 1][1] + red[R_ + 1][2] + red[R_ + 1][3]);
        }
    }
}

__global__ __launch_bounds__(T_) void k_final(float* ws, float* out) {
    __shared__ double redn[4], redd[4];
    const int b = blockIdx.x;
    const int t = threadIdx.x;
    const int wid = t >> 6, lane = t & 63;
    const float* rowsum = ws + OFF_ROWSUM + (size_t)b * N;
    double num = 0.0, den = 0.0;
    #pragma unroll
    for (int q = 0; q < 4; ++q) {
        int j = t + 256 * q;
        double r = (double)rowsum[j];
        float ct = 0.f;
        #pragma unroll
        for (int rep = 0; rep < NREP; ++rep)
            ct += ws[OFF_COLT + (size_t)(b * NREP + rep) * N + j];
        num += (double)ws[OFF_COLSUMM + j] * r;
        den += (double)ct * r;
    }
    #pragma unroll
    for (int o = 32; o > 0; o >>= 1) {
        num += __shfl_down(num, o, 64);
        den += __shfl_down(den, o, 64);
    }
    if (lane == 0) { redn[wid] = num; redd[wid] = den; }
    __syncthreads();
    if (t == 0) {
        double NUM = redn[0] + redn[1] + redn[2] + redn[3];
        double DEN = redd[0] + redd[1] + redd[2] + redd[3];
        double mu = NUM / DEN;
        double r = (double)ws[OFF_SUMM2] - 2.0 * mu * (double)ws[OFF_SUMMT + b]
                 + mu * mu * (double)ws[OFF_SUMTT + b];
        float mx = ws[OFF_MAXM];  // float bits written via uint atomicMax
        double norm = 1048576.0 * (double)mx * (double)mx;
        atomicAdd(out, (float)(sqrt(r / norm) / 8.0));
    }
}

extern "C" void kernel_launch(void* const* d_in, const int* in_sizes, int n_in,
                              void* d_out, int out_size, void* d_ws, size_t ws_size,
                              hipStream_t stream) {
    const float* pred = (const float*)d_in[0];   // [8, 2048]
    const float* M = (const float*)d_in[2];      // [1024, 1024]
    float* ws = (float*)d_ws;
    float* out = (float*)d_out;

    k_prep<<<4, T_, 0, stream>>>(ws, out);
    dim3 grid(GX, B_ + 1);
    k_row<<<grid, T_, 0, stream>>>(pred, M, ws);
    k_final<<<B_, T_, 0, stream>>>(ws, out);
}